// Round 11
// baseline (259.982 us; speedup 1.0000x reference)
//
#include <hip/hip_runtime.h>
#include <stdint.h>

#define C_IN 256
#define C_MID 64
#define KOFF 9

typedef __attribute__((ext_vector_type(8))) short bf16x8;   // 8 bf16 = 4 VGPRs
typedef __attribute__((ext_vector_type(4))) short short4v;  // 8 B packed bf16x4
typedef __attribute__((ext_vector_type(4))) float f32x4;    // MFMA C/D
typedef __attribute__((ext_vector_type(4))) float float4v;

// fp32 -> bf16 round-to-nearest-even
__device__ inline unsigned short f2bf(float f) {
    union { float f; unsigned u; } x; x.f = f;
    unsigned r = x.u + 0x7FFFu + ((x.u >> 16) & 1u);
    return (unsigned short)(r >> 16);
}

// ---------------------------------------------------------------------------
// prep (unchanged):
//   w1t[n][k] = bf16(w1[k][n] * s1[n])          [64][256]   16384 shorts
//   w2t[k][d][c] = bf16(w2[k][c][d] * s2[d])    [9][64][64] 36864 shorts
//   w3t[e][c] = bf16(w3[c][e] * s3[e])          [256][64]   16384 shorts
// ---------------------------------------------------------------------------
__global__ void prep_kernel(const float* __restrict__ w1, const float* __restrict__ s1,
                            const float* __restrict__ w2, const float* __restrict__ s2,
                            const float* __restrict__ w3, const float* __restrict__ s3,
                            unsigned short* __restrict__ w1t,
                            unsigned short* __restrict__ w2t,
                            unsigned short* __restrict__ w3t,
                            unsigned short* __restrict__ zrow) {
    int tid = blockIdx.x * blockDim.x + threadIdx.x;
    int stride = gridDim.x * blockDim.x;
    for (int i = tid; i < C_MID * C_IN; i += stride) {
        int n = i / C_IN, k = i % C_IN;
        w1t[i] = f2bf(w1[k * C_MID + n] * s1[n]);
    }
    for (int i = tid; i < KOFF * C_MID * C_MID; i += stride) {
        int k = i / (C_MID * C_MID);
        int r = i % (C_MID * C_MID);
        int d = r / C_MID, c = r % C_MID;
        w2t[i] = f2bf(w2[(k * C_MID + c) * C_MID + d] * s2[d]);
    }
    for (int i = tid; i < C_IN * C_MID; i += stride) {
        int e = i / C_MID, c = i % C_MID;
        w3t[i] = f2bf(w3[c * C_IN + e] * s3[e]);
    }
    for (int i = tid; i < C_MID; i += stride) zrow[i] = 0;
}

// ---------------------------------------------------------------------------
// conv1 v12 (R9-proven, part of the 259 µs best): persistent-weights
// grid-stride. Unchanged (control).
// ---------------------------------------------------------------------------
__global__ __launch_bounds__(256, 4) void conv1_kernel(
    const float* __restrict__ feat, const unsigned short* __restrict__ w1t,
    const float* __restrict__ b1, unsigned short* __restrict__ out1,
    int N, int ntiles)
{
    __shared__ __align__(16) unsigned short sW1[16384];      // 32768 B

    int t = threadIdx.x;
    int wave = t >> 6;
    int lane = t & 63;
    int l15 = lane & 15;
    int quad = lane >> 4;

    const bf16x8* w1c = reinterpret_cast<const bf16x8*>(w1t);
    bf16x8* sW1c = reinterpret_cast<bf16x8*>(sW1);
#pragma unroll
    for (int it = 0; it < 8; ++it) {
        int s = it * 256 + t;
        int l = s & 15, ct = (s >> 4) & 3, q = (s >> 6) & 3, kk = s >> 8;
        sW1c[s] = w1c[(ct * 16 + l) * 32 + kk * 4 + q];
    }
    __syncthreads();                                         // only barrier

    for (int tile = blockIdx.x; tile < ntiles; tile += gridDim.x) {
        int site = tile * 64 + wave * 16 + l15;
        int sitec = site < N ? site : (N - 1);

        float4v fr0[8];
#pragma unroll
        for (int kk = 0; kk < 4; ++kk) {
            const float4v* p = reinterpret_cast<const float4v*>(
                feat + (size_t)sitec * C_IN + kk * 32 + quad * 8);
            fr0[kk * 2] = p[0];
            fr0[kk * 2 + 1] = p[1];
        }
        __builtin_amdgcn_sched_barrier(0);

        float4v fr1[8];
#pragma unroll
        for (int kk = 0; kk < 4; ++kk) {
            const float4v* p = reinterpret_cast<const float4v*>(
                feat + (size_t)sitec * C_IN + (kk + 4) * 32 + quad * 8);
            fr1[kk * 2] = p[0];
            fr1[kk * 2 + 1] = p[1];
        }
        __builtin_amdgcn_sched_barrier(0);

        f32x4 acc[4] = {};
#pragma unroll
        for (int kk = 0; kk < 4; ++kk) {
            union { unsigned short s[8]; bf16x8 v; } ua;
#pragma unroll
            for (int j = 0; j < 4; ++j) {
                ua.s[j] = f2bf(fr0[kk * 2][j]);
                ua.s[4 + j] = f2bf(fr0[kk * 2 + 1][j]);
            }
#pragma unroll
            for (int ct = 0; ct < 4; ++ct) {
                bf16x8 fa = sW1c[((kk * 4 + quad) * 4 + ct) * 16 + l15];
                acc[ct] = __builtin_amdgcn_mfma_f32_16x16x32_bf16(fa, ua.v, acc[ct], 0, 0, 0);
            }
        }
#pragma unroll
        for (int kk = 0; kk < 4; ++kk) {
            union { unsigned short s[8]; bf16x8 v; } ua;
#pragma unroll
            for (int j = 0; j < 4; ++j) {
                ua.s[j] = f2bf(fr1[kk * 2][j]);
                ua.s[4 + j] = f2bf(fr1[kk * 2 + 1][j]);
            }
#pragma unroll
            for (int ct = 0; ct < 4; ++ct) {
                bf16x8 fa = sW1c[(((kk + 4) * 4 + quad) * 4 + ct) * 16 + l15];
                acc[ct] = __builtin_amdgcn_mfma_f32_16x16x32_bf16(fa, ua.v, acc[ct], 0, 0, 0);
            }
        }
        if (site < N) {
#pragma unroll
            for (int ct = 0; ct < 4; ++ct) {
                float4v bb = *reinterpret_cast<const float4v*>(b1 + ct * 16 + quad * 4);
                union { unsigned short s[4]; short4v v; } o;
#pragma unroll
                for (int reg = 0; reg < 4; ++reg)
                    o.s[reg] = f2bf(fmaxf(acc[ct][reg] + bb[reg], 0.f));
                *reinterpret_cast<short4v*>(out1 + (size_t)site * C_MID + ct * 16 + quad * 4) = o.v;
            }
        }
    }
}

// ---------------------------------------------------------------------------
// conv23 v14: PERSISTENT, all weights LDS-resident, ZERO barriers in the
// tile loop (the conv1-v12 pattern — the only proven winner — at full
// scale). LDS = w2 73728 + w3 32768 + mid 18432 = 124928 B (gfx950 allows
// up to 160 KB/workgroup). 512 thr / 8 waves / 128 sites/tile; grid 256 =
// 1 block/CU; grid-stride over tiles. Per-tile dataflow is the R0-proven
// sequence (ga pin -> 72 MFMAs -> mid -> rf pin -> 32 MFMAs -> store).
// mid RAW is intra-wave (v9-proven correct) -> no barrier. nbr read
// per-thread (clamped addr + select), next tile's nbr prefetched under the
// MFMAs. nt policy bits kept from v13. (512,2): VGPR cap 256, peak ~130.
// ---------------------------------------------------------------------------
__global__ __launch_bounds__(512, 2) void conv23_kernel(
    const float* __restrict__ feat, const int* __restrict__ nbr,
    const unsigned short* __restrict__ out1, const unsigned short* __restrict__ w2t,
    const float* __restrict__ b2, const unsigned short* __restrict__ w3t,
    const float* __restrict__ b3, float* __restrict__ out, int N, int ntiles)
{
    __shared__ __align__(16) unsigned short sW[53248];       // 106496 B: w2 4608 + w3 2048 chunks
    __shared__ __align__(16) unsigned short sMid[128 * 72];  // 18432 B

    int t = threadIdx.x;
    int wave = t >> 6;
    int lane = t & 63;
    int l15 = lane & 15;
    int quad = lane >> 4;
    int rt = wave * 16 + l15;                                // 0..127

    bf16x8* sWc = reinterpret_cast<bf16x8*>(sW);
    const bf16x8* w2c = reinterpret_cast<const bf16x8*>(w2t);
    const bf16x8* w3c = reinterpret_cast<const bf16x8*>(w3t);

    // ---- stage ALL weights once. w2: 4608 chunks (9/thread), layout
    //      [k][kk][quad][ct][l15] identical to R0's per-phase layout ----
#pragma unroll
    for (int it = 0; it < 9; ++it) {
        int s = it * 512 + t;
        int l = s & 15, ct = (s >> 4) & 3, q = (s >> 6) & 3, kk = (s >> 8) & 1, k = s >> 9;
        sWc[s] = w2c[k * 512 + (ct * 16 + l) * 8 + kk * 4 + q];
    }
    // w3: 2048 chunks at offset 4608 (4/thread), R0's B-phase layout
#pragma unroll
    for (int it = 0; it < 4; ++it) {
        int s = it * 512 + t;
        int l = s & 15, c2 = (s >> 4) & 15, q = (s >> 8) & 3, kk = (s >> 10) & 1;
        sWc[4608 + s] = w3c[(c2 * 16 + l) * 8 + kk * 4 + q];
    }
    __syncthreads();                                         // ONLY barrier

    // ---- prologue: first tile's rulebook row ----
    int nb[KOFF];
    {
        int site0 = blockIdx.x * 128 + rt;
        bool v0 = site0 < N;
        int base0 = v0 ? site0 * KOFF : 0;
#pragma unroll
        for (int k = 0; k < KOFF; ++k) {
            int tmp = nbr[base0 + k];
            nb[k] = v0 ? tmp : N;
        }
    }

    for (int tile = blockIdx.x; tile < ntiles; tile += gridDim.x) {
        int site = tile * 128 + rt;
        int sitec = site < N ? site : (N - 1);

        // ---- pin 18 gathers (R0-exact per thread) ----
        bf16x8 ga[KOFF][2];
#pragma unroll
        for (int k = 0; k < KOFF; ++k) {
            const bf16x8* pg = reinterpret_cast<const bf16x8*>(
                out1 + (size_t)nb[k] * C_MID + quad * 8);
            ga[k][0] = pg[0];
            ga[k][1] = pg[4];
        }
        __builtin_amdgcn_sched_barrier(0);

        // ---- prefetch next tile's rulebook row (drains under MFMAs) ----
        int nnb[KOFF];
        {
            int ntile = tile + gridDim.x;
            int nsite = ntile * 128 + rt;
            bool v = (ntile < ntiles) && (nsite < N);
            int nbase = v ? nsite * KOFF : 0;
#pragma unroll
            for (int k = 0; k < KOFF; ++k) {
                int tmp = nbr[nbase + k];
                nnb[k] = v ? tmp : N;
            }
        }
        __builtin_amdgcn_sched_barrier(0);

        // ---- conv2: 72 MFMAs from resident sW2, no staging, no barrier ----
        f32x4 acc2[4] = {};
#pragma unroll
        for (int k = 0; k < KOFF; ++k) {
#pragma unroll
            for (int kk = 0; kk < 2; ++kk) {
#pragma unroll
                for (int ct = 0; ct < 4; ++ct) {
                    bf16x8 fa = sWc[((k * 2 + kk) * 4 + quad) * 64 + ct * 16 + l15];
                    acc2[ct] = __builtin_amdgcn_mfma_f32_16x16x32_bf16(fa, ga[k][kk], acc2[ct], 0, 0, 0);
                }
            }
        }

        // ---- bn2+relu -> mid (pitch 72; intra-wave RAW, v9-proven) ----
#pragma unroll
        for (int ct = 0; ct < 4; ++ct) {
            float4v bb = *reinterpret_cast<const float4v*>(b2 + ct * 16 + quad * 4);
            union { unsigned short s[4]; short4v v; } o;
#pragma unroll
            for (int reg = 0; reg < 4; ++reg)
                o.s[reg] = f2bf(fmaxf(acc2[ct][reg] + bb[reg], 0.f));
            *reinterpret_cast<short4v*>(&sMid[rt * 72 + ct * 16 + quad * 4]) = o.v;
        }

        // ---- pin rf (nt: streaming, keep out of L2) ----
        float4v rf[16];
#pragma unroll
        for (int c2 = 0; c2 < 16; ++c2)
            rf[c2] = __builtin_nontemporal_load(reinterpret_cast<const float4v*>(
                feat + (size_t)sitec * C_IN + c2 * 16 + quad * 4));
        __builtin_amdgcn_sched_barrier(0);

        // ---- conv3: fb from own-wave mid rows; w3 resident at chunk 4608 ----
        f32x4 acc3[16] = {};
#pragma unroll
        for (int kk = 0; kk < 2; ++kk) {
            bf16x8 fb = *reinterpret_cast<const bf16x8*>(
                &sMid[rt * 72 + kk * 32 + quad * 8]);
#pragma unroll
            for (int c2 = 0; c2 < 16; ++c2) {
                bf16x8 fa = sWc[4608 + ((kk * 4 + quad) * 16 + c2) * 16 + l15];
                acc3[c2] = __builtin_amdgcn_mfma_f32_16x16x32_bf16(fa, fb, acc3[c2], 0, 0, 0);
            }
        }
        if (site < N) {
#pragma unroll
            for (int c2 = 0; c2 < 16; ++c2) {
                float4v bb = *reinterpret_cast<const float4v*>(b3 + c2 * 16 + quad * 4);
                float4v o;
#pragma unroll
                for (int reg = 0; reg < 4; ++reg)
                    o[reg] = fmaxf(acc3[c2][reg] + bb[reg] + rf[c2][reg], 0.f);
                __builtin_nontemporal_store(o, reinterpret_cast<float4v*>(
                    out + (size_t)site * C_IN + c2 * 16 + quad * 4));
            }
        }
        // ---- rotate prefetched rulebook ----
#pragma unroll
        for (int k = 0; k < KOFF; ++k) nb[k] = nnb[k];
    }
}

extern "C" void kernel_launch(void* const* d_in, const int* in_sizes, int n_in,
                              void* d_out, int out_size, void* d_ws, size_t ws_size,
                              hipStream_t stream) {
    const float* feat = (const float*)d_in[0];
    const int*   nbr  = (const int*)d_in[1];
    const float* w1   = (const float*)d_in[2];
    const float* s1   = (const float*)d_in[3];
    const float* b1   = (const float*)d_in[4];
    const float* w2   = (const float*)d_in[5];
    const float* s2   = (const float*)d_in[6];
    const float* b2   = (const float*)d_in[7];
    const float* w3   = (const float*)d_in[8];
    const float* s3   = (const float*)d_in[9];
    const float* b3   = (const float*)d_in[10];
    float* out = (float*)d_out;
    int N = in_sizes[0] / C_IN;

    char* ws = (char*)d_ws;
    unsigned short* w1t  = (unsigned short*)(ws);                    // 32768 B
    unsigned short* w2t  = (unsigned short*)(ws + 32768);            // 73728 B
    unsigned short* w3t  = (unsigned short*)(ws + 32768 + 73728);    // 32768 B
    unsigned short* out1 = (unsigned short*)(ws + 139264);           // (N+1)*64*2 B

    prep_kernel<<<80, 256, 0, stream>>>(w1, s1, w2, s2, w3, s3, w1t, w2t, w3t,
                                        out1 + (size_t)N * C_MID);
    int ntiles1 = (N + 63) / 64;
    int nblk1 = ntiles1 < 1024 ? ntiles1 : 1024;
    conv1_kernel<<<nblk1, 256, 0, stream>>>(feat, w1t, b1, out1, N, ntiles1);
    int ntiles23 = (N + 127) / 128;
    int nblk23 = ntiles23 < 256 ? ntiles23 : 256;
    conv23_kernel<<<nblk23, 512, 0, stream>>>(feat, nbr, out1, w2t, b2, w3t, b3, out,
                                              N, ntiles23);
}